// Round 5
// baseline (116.887 us; speedup 1.0000x reference)
//
#include <hip/hip_runtime.h>
#include <stdint.h>

#define NP 100000
#define MP 32
#define OC 64
#define PPB 32                    // pillars per LDS chunk (32*512B = 16KB per buffer)
#define NCHUNK (NP / PPB)         // 3125 (exact)
#define GRID1 1024                // exactly 4 blocks/CU resident
#define BNEPS 0.001f
#define FIXS_S 65536.0f           // 2^16 fixed-point for Sigma h
#define FIXS_Q 256.0f             // 2^8  fixed-point for Sigma h^2 (no int64 overflow)
#define MTOT 3200000.0

typedef __attribute__((address_space(3))) uint32_t as3_u32;
typedef const __attribute__((address_space(1))) uint32_t as1_u32;

// ---------------------------------------------------------------------------
// Pass 1: double-buffered LDS staging. Per chunk: barrier -> issue next-chunk
// global_load_lds (in flight across the whole compute phase) -> compute current
// chunk from LDS broadcasts. Lane = output channel; wave owns 8 pillars/chunk.
// ---------------------------------------------------------------------------
__global__ __launch_bounds__(256, 4) void sap_pass1(
    const float* __restrict__ feat, const float* __restrict__ W,
    const float* __restrict__ gamma, const int* __restrict__ nump,
    const int* __restrict__ coors, float* __restrict__ hsel,
    unsigned long long* __restrict__ accum)
{
    __shared__ float lds[2][PPB * MP * 4];   // 2 x 16 KB
    __shared__ float sred[4][128];
    const int tid  = threadIdx.x;
    const int lane = tid & 63;
    const int wid  = tid >> 6;
    const int c = lane;

    // W is (10, 64) row-major. Fold cluster/center weights: W2 = W[k]+W[4+k]+W[7+k].
    float w2[4], wcl[3], wce[3];
    w2[3] = W[3 * OC + c];
    #pragma unroll
    for (int k = 0; k < 3; ++k) {
        wcl[k] = W[(4 + k) * OC + c];
        wce[k] = W[(7 + k) * OC + c];
        w2[k]  = W[k * OC + c] + wcl[k] + wce[k];
    }
    // Fold sign(gamma): track a running MAX of d' = sgn*d only.
    const float sgn = (gamma[c] >= 0.0f) ? 1.0f : -1.0f;
    #pragma unroll
    for (int k = 0; k < 3; ++k) { wcl[k] *= sgn; wce[k] *= sgn; w2[k] *= sgn; }
    w2[3] *= sgn;

    // Stage one 16KB chunk: 256 threads x 4 x 16B, linear LDS dest (lane x 16B).
#define STAGE(BUF, CH) {                                                          \
        const char* g = (const char*)feat + (size_t)(CH) * (PPB * MP * 16) + tid * 16; \
        as3_u32* l = (as3_u32*)(&lds[BUF][0]) + tid * 4;                          \
        __builtin_amdgcn_global_load_lds((as1_u32*)(g),         l,        16, 0, 0); \
        __builtin_amdgcn_global_load_lds((as1_u32*)(g + 4096),  l + 1024, 16, 0, 0); \
        __builtin_amdgcn_global_load_lds((as1_u32*)(g + 8192),  l + 2048, 16, 0, 0); \
        __builtin_amdgcn_global_load_lds((as1_u32*)(g + 12288), l + 3072, 16, 0, 0); }

    float accS = 0.0f, accQ = 0.0f;
    int cur = 0;

    STAGE(0, blockIdx.x)                         // prologue prefetch

    for (int chunk = blockIdx.x; chunk < NCHUNK; chunk += GRID1) {
        __syncthreads();                         // drains vmcnt: lds[cur] resident;
                                                 // all waves done reading lds[cur^1]
        const int nxtc = chunk + GRID1;
        if (nxtc < NCHUNK) STAGE(cur ^ 1, nxtc)  // in flight during compute below

        for (int jj = 0; jj < 8; ++jj) {
            const int n = chunk * PPB + wid * 8 + jj;      // wave-uniform
            const int cnt = nump[n];                       // uniform -> s_load
            const float4* __restrict__ f4 =
                reinterpret_cast<const float4*>(&lds[cur][(wid * 8 + jj) * MP * 4]);

            float sx0=0.f,sy0=0.f,sz0=0.f,sw0=0.f, q0=0.f, m0=-3.0e38f;
            float sx1=0.f,sy1=0.f,sz1=0.f,sw1=0.f, q1=0.f, m1=-3.0e38f;
            float sx2=0.f,sy2=0.f,sz2=0.f,sw2=0.f, q2=0.f, m2=-3.0e38f;
            float sx3=0.f,sy3=0.f,sz3=0.f,sw3=0.f, q3=0.f, m3=-3.0e38f;

#define PT(J, S) { const float4 f = f4[p + J];                                  \
            sx##S += f.x; sy##S += f.y; sz##S += f.z; sw##S += f.w;             \
            const float d = fmaf(f.x, w2[0], fmaf(f.y, w2[1],                   \
                            fmaf(f.z, w2[2], f.w * w2[3])));                    \
            q##S = fmaf(d, d, q##S); m##S = fmaxf(m##S, d); }

            int p = 0;
            for (; p + 4 <= cnt; p += 4) { PT(0,0) PT(1,1) PT(2,2) PT(3,3) }
            for (; p < cnt; ++p)          { PT(0,0) }
#undef PT

            const float sf0 = (sx0 + sx1) + (sx2 + sx3);
            const float sf1 = (sy0 + sy1) + (sy2 + sy3);
            const float sf2 = (sz0 + sz1) + (sz2 + sz3);
            const float sf3 = (sw0 + sw1) + (sw2 + sw3);
            const float q   = (q0 + q1) + (q2 + q3);
            const float m   = fmaxf(fmaxf(m0, m1), fmaxf(m2, m3));

            const float fcnt = (float)cnt;
            const float rc = 1.0f / fcnt;
            const float cz = ((float)coors[4 * n + 1] + 0.5f) * 0.2f;
            const float cy = ((float)coors[4 * n + 2] + 0.5f) * 0.2f;
            const float cx = ((float)coors[4 * n + 3] + 0.5f) * 4.0f;
            // bias' = sgn * (-mean.Wcl - center.Wce)  (sgn folded into wcl/wce)
            const float bias = -(sf0 * rc * wcl[0] + sf1 * rc * wcl[1] + sf2 * rc * wcl[2])
                               - (cz * wce[0] + cy * wce[1] + cx * wce[2]);
            const float ssum = sf0 * w2[0] + sf1 * w2[1] + sf2 * w2[2] + sf3 * w2[3];

            float hm = m + bias;                  // max over active of h' = sgn*h
            if (cnt < MP) hm = fmaxf(hm, 0.0f);   // masked positions contribute h=0
            hsel[(size_t)n * OC + c] = sgn * hm;

            accS += sgn * (ssum + fcnt * bias);                   // Sigma h
            accQ += q + 2.0f * bias * ssum + fcnt * bias * bias;  // Sigma h^2
        }
        cur ^= 1;
    }
#undef STAGE

    sred[wid][c]      = accS;
    sred[wid][64 + c] = accQ;
    __syncthreads();
    if (wid == 0) {
        const float s  = sred[0][lane] + sred[1][lane] + sred[2][lane] + sred[3][lane];
        const float sq = sred[0][64+lane] + sred[1][64+lane] + sred[2][64+lane] + sred[3][64+lane];
        atomicAdd(&accum[lane],      (unsigned long long)(long long)llrintf(s  * FIXS_S));
        atomicAdd(&accum[64 + lane], (unsigned long long)(long long)llrintf(sq * FIXS_Q));
    }
}

// ---------------------------------------------------------------------------
// Finalize BN stats -> per-channel scale/shift (128 floats).
// ---------------------------------------------------------------------------
__global__ void sap_finalize(const unsigned long long* __restrict__ accum,
                             const float* __restrict__ gamma,
                             const float* __restrict__ beta,
                             float* __restrict__ scsh)
{
    const int c = threadIdx.x;
    const double S = (double)(long long)accum[c]      * (1.0 / 65536.0);
    const double Q = (double)(long long)accum[64 + c] * (1.0 / 256.0);
    const double mu_d = S / MTOT;
    const double var_d = Q / MTOT - mu_d * mu_d;
    const float mu  = (float)mu_d;
    const float sc  = gamma[c] * rsqrtf((float)var_d + BNEPS);
    const float sh  = beta[c] - mu * sc;
    scsh[c]      = sc;
    scsh[64 + c] = sh;
}

// ---------------------------------------------------------------------------
// Pass 2: in-place over d_out: out = relu(scale * hsel + shift).
// ---------------------------------------------------------------------------
__global__ __launch_bounds__(256) void sap_pass2(const float* __restrict__ scsh,
                                                 float* __restrict__ out)
{
    const int idx = blockIdx.x * 256 + threadIdx.x;
    if (idx >= (NP * OC) / 4) return;
    float4 h = reinterpret_cast<float4*>(out)[idx];
    const int ci = idx & 15;                               // channel quad (64ch/4)
    const float4 sc = reinterpret_cast<const float4*>(scsh)[ci];
    const float4 sh = reinterpret_cast<const float4*>(scsh + 64)[ci];
    float4 o;
    o.x = fmaxf(fmaf(h.x, sc.x, sh.x), 0.0f);
    o.y = fmaxf(fmaf(h.y, sc.y, sh.y), 0.0f);
    o.z = fmaxf(fmaf(h.z, sc.z, sh.z), 0.0f);
    o.w = fmaxf(fmaf(h.w, sc.w, sh.w), 0.0f);
    reinterpret_cast<float4*>(out)[idx] = o;
}

extern "C" void kernel_launch(void* const* d_in, const int* in_sizes, int n_in,
                              void* d_out, int out_size, void* d_ws, size_t ws_size,
                              hipStream_t stream) {
    const float* feat  = (const float*)d_in[0];
    const float* W     = (const float*)d_in[1];
    const float* gamma = (const float*)d_in[2];
    const float* beta  = (const float*)d_in[3];
    const int*   nump  = (const int*)d_in[4];
    const int*   coors = (const int*)d_in[5];
    float* out = (float*)d_out;

    unsigned long long* accum = (unsigned long long*)d_ws;   // 128 * 8B
    float* scsh = (float*)((char*)d_ws + 1024);              // 128 * 4B

    hipMemsetAsync(accum, 0, 1024, stream);
    // Pass 1 writes its per-pillar max/min selection straight into d_out.
    sap_pass1<<<GRID1, 256, 0, stream>>>(feat, W, gamma, nump, coors, out, accum);
    sap_finalize<<<1, 64, 0, stream>>>(accum, gamma, beta, scsh);
    sap_pass2<<<(NP * OC / 4 + 255) / 256, 256, 0, stream>>>(scsh, out);
}

// Round 6
// 97.373 us; speedup vs baseline: 1.2004x; 1.2004x over previous
//
#include <hip/hip_runtime.h>
#include <stdint.h>

#define NP 100000
#define NTASK (NP / 2)            // 50000 wave-tasks, 2 pillars each
#define MP 32
#define OC 64
#define GRID1 2048
#define BNEPS 0.001f
#define FIXS_S 65536.0f           // 2^16 fixed-point for Sigma h
#define FIXS_Q 256.0f             // 2^8  fixed-point for Sigma h^2 (no int64 overflow)
#define MTOT 3200000.0

// Broadcast lane `sl`'s float to all lanes via v_readlane (VALU->SGPR, no LDS).
__device__ __forceinline__ float bcast(float v, int sl) {
    return __int_as_float(__builtin_amdgcn_readlane(__float_as_int(v), sl));
}

// ---------------------------------------------------------------------------
// Pass 1: register-resident, LDS-free point loop.
// Wave-task = 2 pillars. Lane l holds point (l&31) of pillar 2t+(l>>5) as a
// float4 (one coalesced 1KB global load per task). Per point, components are
// broadcast from the owning lane via v_readlane; lane = output channel.
// Emits hsel[n][c] = (gamma>=0 ? max_p h : min_p h) into d_out and global
// Sigma h / Sigma h^2 as deterministic int64 fixed-point atomics.
// ---------------------------------------------------------------------------
__global__ __launch_bounds__(256) void sap_pass1(
    const float* __restrict__ feat, const float* __restrict__ W,
    const float* __restrict__ gamma, const int* __restrict__ nump,
    const int* __restrict__ coors, float* __restrict__ hsel,
    unsigned long long* __restrict__ accum)
{
    __shared__ float sred[4][128];
    const int lane = threadIdx.x & 63;
    const int wid  = threadIdx.x >> 6;
    const int c = lane;

    // W is (10, 64) row-major. Fold cluster/center weights: W2 = W[k]+W[4+k]+W[7+k].
    float w2[4], wcl[3], wce[3];
    w2[3] = W[3 * OC + c];
    #pragma unroll
    for (int k = 0; k < 3; ++k) {
        wcl[k] = W[(4 + k) * OC + c];
        wce[k] = W[(7 + k) * OC + c];
        w2[k]  = W[k * OC + c] + wcl[k] + wce[k];
    }
    // Fold sign(gamma): track a running MAX of d' = sgn*d only.
    const float sgn = (gamma[c] >= 0.0f) ? 1.0f : -1.0f;
    #pragma unroll
    for (int k = 0; k < 3; ++k) { wcl[k] *= sgn; wce[k] *= sgn; w2[k] *= sgn; }
    w2[3] *= sgn;

    const float4* __restrict__ feat4 = reinterpret_cast<const float4*>(feat);
    const int nwaves = GRID1 * 4;

    float accS = 0.0f, accQ = 0.0f;

    int t = blockIdx.x * 4 + wid;
    float4 cur;
    if (t < NTASK) cur = feat4[(size_t)t * 64 + lane];   // lane = point|pillar-half

    for (; t < NTASK; t += nwaves) {
        const int tn = t + nwaves;
        float4 nxt = cur;
        if (tn < NTASK) nxt = feat4[(size_t)tn * 64 + lane];  // prefetch, in flight

        #pragma unroll
        for (int half = 0; half < 2; ++half) {
            const int n = 2 * t + half;              // wave-uniform pillar
            const int cnt = nump[n];                 // uniform -> s_load
            const int lb = half * 32;                // readlane base for this pillar

            // 2 independent accumulator sets for ILP
            float sA0=0.f,sA1=0.f,sA2=0.f,sA3=0.f, qA=0.f, mA=-3.0e38f;
            float sB0=0.f,sB1=0.f,sB2=0.f,sB3=0.f, qB=0.f, mB=-3.0e38f;

            int p = 0;
            for (; p + 2 <= cnt; p += 2) {
                const float x0 = bcast(cur.x, lb + p),     y0 = bcast(cur.y, lb + p);
                const float z0 = bcast(cur.z, lb + p),     u0 = bcast(cur.w, lb + p);
                const float x1 = bcast(cur.x, lb + p + 1), y1 = bcast(cur.y, lb + p + 1);
                const float z1 = bcast(cur.z, lb + p + 1), u1 = bcast(cur.w, lb + p + 1);
                sA0 += x0; sA1 += y0; sA2 += z0; sA3 += u0;
                sB0 += x1; sB1 += y1; sB2 += z1; sB3 += u1;
                const float d0 = fmaf(x0, w2[0], fmaf(y0, w2[1], fmaf(z0, w2[2], u0 * w2[3])));
                const float d1 = fmaf(x1, w2[0], fmaf(y1, w2[1], fmaf(z1, w2[2], u1 * w2[3])));
                qA = fmaf(d0, d0, qA); mA = fmaxf(mA, d0);
                qB = fmaf(d1, d1, qB); mB = fmaxf(mB, d1);
            }
            if (p < cnt) {
                const float x0 = bcast(cur.x, lb + p), y0 = bcast(cur.y, lb + p);
                const float z0 = bcast(cur.z, lb + p), u0 = bcast(cur.w, lb + p);
                sA0 += x0; sA1 += y0; sA2 += z0; sA3 += u0;
                const float d0 = fmaf(x0, w2[0], fmaf(y0, w2[1], fmaf(z0, w2[2], u0 * w2[3])));
                qA = fmaf(d0, d0, qA); mA = fmaxf(mA, d0);
            }

            const float sf0 = sA0 + sB0, sf1 = sA1 + sB1;
            const float sf2 = sA2 + sB2, sf3 = sA3 + sB3;
            const float q   = qA + qB;
            const float m   = fmaxf(mA, mB);

            const float fcnt = (float)cnt;
            const float rc = 1.0f / fcnt;
            const float cz = ((float)coors[4 * n + 1] + 0.5f) * 0.2f;
            const float cy = ((float)coors[4 * n + 2] + 0.5f) * 0.2f;
            const float cx = ((float)coors[4 * n + 3] + 0.5f) * 4.0f;
            // bias' = sgn * (-mean.Wcl - center.Wce)  (sgn folded into wcl/wce)
            const float bias = -(sf0 * rc * wcl[0] + sf1 * rc * wcl[1] + sf2 * rc * wcl[2])
                               - (cz * wce[0] + cy * wce[1] + cx * wce[2]);
            const float ssum = sf0 * w2[0] + sf1 * w2[1] + sf2 * w2[2] + sf3 * w2[3];

            float hm = m + bias;                  // max over active of h' = sgn*h
            if (cnt < MP) hm = fmaxf(hm, 0.0f);   // masked positions contribute h=0
            hsel[(size_t)n * OC + c] = sgn * hm;

            accS += sgn * (ssum + fcnt * bias);                   // Sigma h
            accQ += q + 2.0f * bias * ssum + fcnt * bias * bias;  // Sigma h^2
        }
        cur = nxt;
    }

    sred[wid][c]      = accS;
    sred[wid][64 + c] = accQ;
    __syncthreads();
    if (wid == 0) {
        const float s  = sred[0][lane] + sred[1][lane] + sred[2][lane] + sred[3][lane];
        const float sq = sred[0][64+lane] + sred[1][64+lane] + sred[2][64+lane] + sred[3][64+lane];
        atomicAdd(&accum[lane],      (unsigned long long)(long long)llrintf(s  * FIXS_S));
        atomicAdd(&accum[64 + lane], (unsigned long long)(long long)llrintf(sq * FIXS_Q));
    }
}

// ---------------------------------------------------------------------------
// Finalize BN stats -> per-channel scale/shift (128 floats).
// ---------------------------------------------------------------------------
__global__ void sap_finalize(const unsigned long long* __restrict__ accum,
                             const float* __restrict__ gamma,
                             const float* __restrict__ beta,
                             float* __restrict__ scsh)
{
    const int c = threadIdx.x;
    const double S = (double)(long long)accum[c]      * (1.0 / 65536.0);
    const double Q = (double)(long long)accum[64 + c] * (1.0 / 256.0);
    const double mu_d = S / MTOT;
    const double var_d = Q / MTOT - mu_d * mu_d;
    const float mu  = (float)mu_d;
    const float sc  = gamma[c] * rsqrtf((float)var_d + BNEPS);
    const float sh  = beta[c] - mu * sc;
    scsh[c]      = sc;
    scsh[64 + c] = sh;
}

// ---------------------------------------------------------------------------
// Pass 2: in-place over d_out: out = relu(scale * hsel + shift).
// ---------------------------------------------------------------------------
__global__ __launch_bounds__(256) void sap_pass2(const float* __restrict__ scsh,
                                                 float* __restrict__ out)
{
    const int idx = blockIdx.x * 256 + threadIdx.x;
    if (idx >= (NP * OC) / 4) return;
    float4 h = reinterpret_cast<float4*>(out)[idx];
    const int ci = idx & 15;                               // channel quad (64ch/4)
    const float4 sc = reinterpret_cast<const float4*>(scsh)[ci];
    const float4 sh = reinterpret_cast<const float4*>(scsh + 64)[ci];
    float4 o;
    o.x = fmaxf(fmaf(h.x, sc.x, sh.x), 0.0f);
    o.y = fmaxf(fmaf(h.y, sc.y, sh.y), 0.0f);
    o.z = fmaxf(fmaf(h.z, sc.z, sh.z), 0.0f);
    o.w = fmaxf(fmaf(h.w, sc.w, sh.w), 0.0f);
    reinterpret_cast<float4*>(out)[idx] = o;
}

extern "C" void kernel_launch(void* const* d_in, const int* in_sizes, int n_in,
                              void* d_out, int out_size, void* d_ws, size_t ws_size,
                              hipStream_t stream) {
    const float* feat  = (const float*)d_in[0];
    const float* W     = (const float*)d_in[1];
    const float* gamma = (const float*)d_in[2];
    const float* beta  = (const float*)d_in[3];
    const int*   nump  = (const int*)d_in[4];
    const int*   coors = (const int*)d_in[5];
    float* out = (float*)d_out;

    unsigned long long* accum = (unsigned long long*)d_ws;   // 128 * 8B
    float* scsh = (float*)((char*)d_ws + 1024);              // 128 * 4B

    hipMemsetAsync(accum, 0, 1024, stream);
    // Pass 1 writes its per-pillar max/min selection straight into d_out.
    sap_pass1<<<GRID1, 256, 0, stream>>>(feat, W, gamma, nump, coors, out, accum);
    sap_finalize<<<1, 64, 0, stream>>>(accum, gamma, beta, scsh);
    sap_pass2<<<(NP * OC / 4 + 255) / 256, 256, 0, stream>>>(scsh, out);
}

// Round 7
// 89.412 us; speedup vs baseline: 1.3073x; 1.0890x over previous
//
#include <hip/hip_runtime.h>
#include <stdint.h>

#define NP 100000
#define NTASK (NP / 2)            // 50000 wave-tasks, 2 pillars each
#define MP 32
#define OC 64
#define GRID1 2048
#define NWAVES (GRID1 * 4)
#define BNEPS 0.001f
#define FIXS_S 65536.0f           // 2^16 fixed-point for Sigma h
#define FIXS_Q 256.0f             // 2^8  fixed-point for Sigma h^2 (no int64 overflow)
#define MTOT 3200000.0

#define SWZF(v, pat) __int_as_float(__builtin_amdgcn_ds_swizzle(__float_as_int(v), (pat)))
#define RLF(v, l)    __int_as_float(__builtin_amdgcn_readlane(__float_as_int(v), (l)))

// ---------------------------------------------------------------------------
// Per-pillar point loop. All point data (b0..b3 quads) comes from UNIFORM
// scalar loads (SGPRs) -> broadcast is free on the VALU. Per point: 4 d-FMAs +
// 1 q-FMA + 1 max = 6 VALU. Quad-ahead software prefetch hides SMEM latency.
// ---------------------------------------------------------------------------
__device__ __forceinline__ void do_pillar(
    const float4* __restrict__ fp, const int cnt,
    float4 b0, float4 b1, float4 b2, float4 b3,
    const float S0, const float S1, const float S2, const float S3,
    const int iz, const int iy, const int ix,
    const float w20, const float w21, const float w22, const float w23,
    const float wc0, const float wc1, const float wc2,
    const float we0, const float we1, const float we2,
    const float sgn, float* __restrict__ outp, float& accS, float& accQ)
{
    float q0 = 0.f, q1 = 0.f, m0 = -3.0e38f, m1 = -3.0e38f;
    const int cq = cnt & ~3;
    int p = 0;
#define PTQ(B, S) { const float d = fmaf(B.x, w20, fmaf(B.y, w21,               \
                          fmaf(B.z, w22, B.w * w23)));                           \
                    q##S = fmaf(d, d, q##S); m##S = fmaxf(m##S, d); }
    while (p < cq) {                       // uniform trip count
        const int pn = (p + 8 <= MP) ? (p + 4) : 0;      // safe prefetch index
        const float4 n0 = fp[pn], n1 = fp[pn + 1], n2 = fp[pn + 2], n3 = fp[pn + 3];
        PTQ(b0, 0) PTQ(b1, 1) PTQ(b2, 0) PTQ(b3, 1)
        b0 = n0; b1 = n1; b2 = n2; b3 = n3;
        p += 4;
    }
    const int rem = cnt - cq;              // b holds quad(cq) here
    if (rem > 0) PTQ(b0, 0)
    if (rem > 1) PTQ(b1, 1)
    if (rem > 2) PTQ(b2, 0)
#undef PTQ
    const float q = q0 + q1;
    const float m = fmaxf(m0, m1);
    const float fcnt = (float)cnt;
    const float rc = __builtin_amdgcn_rcpf(fcnt);
    const float cz = ((float)iz + 0.5f) * 0.2f;
    const float cy = ((float)iy + 0.5f) * 0.2f;
    const float cx = ((float)ix + 0.5f) * 4.0f;
    // bias' = sgn*(-mean.Wcl - center.Wce); sgn pre-folded into wc/we/w2
    const float mt   = fmaf(S2, wc2, fmaf(S1, wc1, S0 * wc0));
    const float bias = -fmaf(mt, rc, fmaf(cz, we0, fmaf(cy, we1, cx * we2)));
    const float ssum = fmaf(S3, w23, fmaf(S2, w22, fmaf(S1, w21, S0 * w20)));
    float hm = m + bias;                   // max over active of h' = sgn*h
    if (cnt < MP) hm = fmaxf(hm, 0.0f);    // masked positions contribute h=0
    *outp = sgn * hm;
    const float fb = fcnt * bias;
    accS = fmaf(sgn, ssum + fb, accS);                          // Sigma h
    accQ += fmaf(fb, bias, fmaf(bias + bias, ssum, q));         // Sigma h^2
}

// ---------------------------------------------------------------------------
// Pass 1: wave-task = 2 pillars; lane = output channel.
// Coalesced vector load (lane = point) feeds a masked ds_swizzle butterfly for
// the per-pillar feature sums (LDS pipe, otherwise idle). Point d/q/max chain
// runs on scalar-loaded (SMEM) broadcasts.
// ---------------------------------------------------------------------------
__global__ __launch_bounds__(256) void sap_pass1(
    const float* __restrict__ feat, const float* __restrict__ W,
    const float* __restrict__ gamma, const int* __restrict__ nump,
    const int* __restrict__ coors, float* __restrict__ hsel,
    unsigned long long* __restrict__ accum)
{
    __shared__ float sred[4][128];
    const int lane = threadIdx.x & 63;
    const int wid  = threadIdx.x >> 6;
    const int c = lane;
    const int pi = lane & 31;
    const bool hiHalf = lane >= 32;

    // W is (10,64) row-major. Fold cluster/center: W2 = W[k] + W[4+k] + W[7+k].
    float w2[4], wcl[3], wce[3];
    w2[3] = W[3 * OC + c];
    #pragma unroll
    for (int k = 0; k < 3; ++k) {
        wcl[k] = W[(4 + k) * OC + c];
        wce[k] = W[(7 + k) * OC + c];
        w2[k]  = W[k * OC + c] + wcl[k] + wce[k];
    }
    const float sgn = (gamma[c] >= 0.0f) ? 1.0f : -1.0f;
    #pragma unroll
    for (int k = 0; k < 3; ++k) { wcl[k] *= sgn; wce[k] *= sgn; w2[k] *= sgn; }
    w2[3] *= sgn;

    const float4* __restrict__ feat4 = reinterpret_cast<const float4*>(feat);

    float accS = 0.0f, accQ = 0.0f;

    int t = blockIdx.x * 4 + wid;
    float4 curv = make_float4(0.f, 0.f, 0.f, 0.f);
    if (t < NTASK) curv = feat4[(size_t)t * 64 + lane];    // lane = point|half

    for (; t < NTASK; t += NWAVES) {
        const int tu = __builtin_amdgcn_readfirstlane(t);  // wave-uniform task
        const int tn = t + NWAVES;
        float4 nxtv = curv;
        if (tn < NTASK) nxtv = feat4[(size_t)tn * 64 + lane];   // vector prefetch

        const int nA = 2 * tu, nB = nA + 1;
        const int cntA = nump[nA], cntB = nump[nB];             // uniform s_load
        const float4* __restrict__ fpA = feat4 + (size_t)nA * MP;
        const float4* __restrict__ fpB = feat4 + (size_t)nB * MP;

        // Issue both pillars' first quads now (SMEM latency overlaps butterfly).
        const float4 a0 = fpA[0], a1 = fpA[1], a2 = fpA[2], a3 = fpA[3];
        const float4 e0 = fpB[0], e1 = fpB[1], e2 = fpB[2], e3 = fpB[3];

        const int izA = coors[4 * nA + 1], iyA = coors[4 * nA + 2], ixA = coors[4 * nA + 3];
        const int izB = coors[4 * nB + 1], iyB = coors[4 * nB + 2], ixB = coors[4 * nB + 3];

        // ---- masked lane-parallel feature sums, 32-lane xor-butterfly
        const int  cntHalf = hiHalf ? cntB : cntA;
        const bool act = pi < cntHalf;
        float s0 = act ? curv.x : 0.0f;
        float s1 = act ? curv.y : 0.0f;
        float s2 = act ? curv.z : 0.0f;
        float s3 = act ? curv.w : 0.0f;
#define RED(pat) { s0 += SWZF(s0, pat); s1 += SWZF(s1, pat);                    \
                   s2 += SWZF(s2, pat); s3 += SWZF(s3, pat); }
        RED(0x041F) RED(0x081F) RED(0x101F) RED(0x201F) RED(0x401F)
#undef RED
        const float sA0 = RLF(s0, 0),  sA1 = RLF(s1, 0),  sA2 = RLF(s2, 0),  sA3 = RLF(s3, 0);
        const float sB0 = RLF(s0, 32), sB1 = RLF(s1, 32), sB2 = RLF(s2, 32), sB3 = RLF(s3, 32);

        do_pillar(fpA, cntA, a0, a1, a2, a3, sA0, sA1, sA2, sA3, izA, iyA, ixA,
                  w2[0], w2[1], w2[2], w2[3], wcl[0], wcl[1], wcl[2],
                  wce[0], wce[1], wce[2], sgn,
                  &hsel[(size_t)nA * OC + c], accS, accQ);
        do_pillar(fpB, cntB, e0, e1, e2, e3, sB0, sB1, sB2, sB3, izB, iyB, ixB,
                  w2[0], w2[1], w2[2], w2[3], wcl[0], wcl[1], wcl[2],
                  wce[0], wce[1], wce[2], sgn,
                  &hsel[(size_t)nB * OC + c], accS, accQ);

        curv = nxtv;
    }

    sred[wid][c]      = accS;
    sred[wid][64 + c] = accQ;
    __syncthreads();
    if (wid == 0) {
        const float s  = sred[0][lane] + sred[1][lane] + sred[2][lane] + sred[3][lane];
        const float sq = sred[0][64+lane] + sred[1][64+lane] + sred[2][64+lane] + sred[3][64+lane];
        atomicAdd(&accum[lane],      (unsigned long long)(long long)llrintf(s  * FIXS_S));
        atomicAdd(&accum[64 + lane], (unsigned long long)(long long)llrintf(sq * FIXS_Q));
    }
}

// ---------------------------------------------------------------------------
// Finalize BN stats -> per-channel scale/shift (128 floats).
// ---------------------------------------------------------------------------
__global__ void sap_finalize(const unsigned long long* __restrict__ accum,
                             const float* __restrict__ gamma,
                             const float* __restrict__ beta,
                             float* __restrict__ scsh)
{
    const int c = threadIdx.x;
    const double S = (double)(long long)accum[c]      * (1.0 / 65536.0);
    const double Q = (double)(long long)accum[64 + c] * (1.0 / 256.0);
    const double mu_d = S / MTOT;
    const double var_d = Q / MTOT - mu_d * mu_d;
    const float mu  = (float)mu_d;
    const float sc  = gamma[c] * rsqrtf((float)var_d + BNEPS);
    const float sh  = beta[c] - mu * sc;
    scsh[c]      = sc;
    scsh[64 + c] = sh;
}

// ---------------------------------------------------------------------------
// Pass 2: in-place over d_out: out = relu(scale * hsel + shift).
// ---------------------------------------------------------------------------
__global__ __launch_bounds__(256) void sap_pass2(const float* __restrict__ scsh,
                                                 float* __restrict__ out)
{
    const int idx = blockIdx.x * 256 + threadIdx.x;
    if (idx >= (NP * OC) / 4) return;
    float4 h = reinterpret_cast<float4*>(out)[idx];
    const int ci = idx & 15;                               // channel quad (64ch/4)
    const float4 sc = reinterpret_cast<const float4*>(scsh)[ci];
    const float4 sh = reinterpret_cast<const float4*>(scsh + 64)[ci];
    float4 o;
    o.x = fmaxf(fmaf(h.x, sc.x, sh.x), 0.0f);
    o.y = fmaxf(fmaf(h.y, sc.y, sh.y), 0.0f);
    o.z = fmaxf(fmaf(h.z, sc.z, sh.z), 0.0f);
    o.w = fmaxf(fmaf(h.w, sc.w, sh.w), 0.0f);
    reinterpret_cast<float4*>(out)[idx] = o;
}

extern "C" void kernel_launch(void* const* d_in, const int* in_sizes, int n_in,
                              void* d_out, int out_size, void* d_ws, size_t ws_size,
                              hipStream_t stream) {
    const float* feat  = (const float*)d_in[0];
    const float* W     = (const float*)d_in[1];
    const float* gamma = (const float*)d_in[2];
    const float* beta  = (const float*)d_in[3];
    const int*   nump  = (const int*)d_in[4];
    const int*   coors = (const int*)d_in[5];
    float* out = (float*)d_out;

    unsigned long long* accum = (unsigned long long*)d_ws;   // 128 * 8B
    float* scsh = (float*)((char*)d_ws + 1024);              // 128 * 4B

    hipMemsetAsync(accum, 0, 1024, stream);
    // Pass 1 writes its per-pillar max/min selection straight into d_out.
    sap_pass1<<<GRID1, 256, 0, stream>>>(feat, W, gamma, nump, coors, out, accum);
    sap_finalize<<<1, 64, 0, stream>>>(accum, gamma, beta, scsh);
    sap_pass2<<<(NP * OC / 4 + 255) / 256, 256, 0, stream>>>(scsh, out);
}

// Round 8
// 81.526 us; speedup vs baseline: 1.4337x; 1.0967x over previous
//
#include <hip/hip_runtime.h>
#include <stdint.h>

#define NP 100000
#define NTASK (NP / 2)            // 50000 wave-tasks, 2 pillars each
#define MP 32
#define OC 64
#define GRID1 2048
#define NWAVES (GRID1 * 4)
#define BNEPS 0.001f
#define FIXS_S 65536.0f           // 2^16 fixed-point for Sigma h
#define FIXS_Q 256.0f             // 2^8  fixed-point for Sigma h^2 bias-part
#define FIXS_G 1048576.0f         // 2^20 fixed-point for global Gram entries
#define MTOT 3200000.0

typedef short bf16x8 __attribute__((ext_vector_type(8)));   // 8 bf16 = 4 VGPRs
typedef float f32x16 __attribute__((ext_vector_type(16)));

union FRAG { uint32_t u[4]; bf16x8 v; };

// v_cvt_pk_bf16_f32: RNE-pack two fp32 -> bf16x2 (lo=src0, hi=src1)
__device__ __forceinline__ uint32_t pkbf16(float lo, float hi) {
    uint32_t r;
    asm("v_cvt_pk_bf16_f32 %0, %1, %2" : "=v"(r) : "v"(lo), "v"(hi));
    return r;
}

// 32-lane sum butterfly on the VALU pipe (DPP) + one swizzle level.
// After: every lane of each 32-lane half holds that half's total.
__device__ __forceinline__ float red32(float v) {
    v += __int_as_float(__builtin_amdgcn_update_dpp(0, __float_as_int(v), 0xB1,  0xF, 0xF, true)); // xor1
    v += __int_as_float(__builtin_amdgcn_update_dpp(0, __float_as_int(v), 0x4E,  0xF, 0xF, true)); // xor2
    v += __int_as_float(__builtin_amdgcn_update_dpp(0, __float_as_int(v), 0x141, 0xF, 0xF, true)); // half_mirror (xor-quad4)
    v += __int_as_float(__builtin_amdgcn_update_dpp(0, __float_as_int(v), 0x140, 0xF, 0xF, true)); // mirror (xor-oct8)
    v += __int_as_float(__builtin_amdgcn_ds_swizzle(__float_as_int(v), 0x401F));                   // xor16
    return v;
}

__device__ __forceinline__ float max16(f32x16 d) {
    const float a = fmaxf(fmaxf(d[0], d[1]),  fmaxf(d[2], d[3]));
    const float b = fmaxf(fmaxf(d[4], d[5]),  fmaxf(d[6], d[7]));
    const float c = fmaxf(fmaxf(d[8], d[9]),  fmaxf(d[10], d[11]));
    const float e = fmaxf(fmaxf(d[12], d[13]), fmaxf(d[14], d[15]));
    return fmaxf(fmaxf(a, b), fmaxf(c, e));
}

// ---------------------------------------------------------------------------
// Pass 1: wave-task = 2 pillars; lane = point|pillar-half for loads,
// lane = channel for outputs. d' = f.w2' via MFMA (bf16, K=4 zero-padded to 16,
// masked rows excluded via C=-3e38). Per-pillar S via DPP butterfly. Sigma d'^2
// via a GLOBAL Gram accumulated per-lane (no per-pillar reduce).
// ---------------------------------------------------------------------------
__global__ __launch_bounds__(256) void sap_pass1(
    const float* __restrict__ feat, const float* __restrict__ W,
    const float* __restrict__ gamma, const int* __restrict__ nump,
    const int* __restrict__ coors, float* __restrict__ hsel,
    unsigned long long* __restrict__ accum)
{
    __shared__ float sred[4][128];
    __shared__ float sredG[4][10];
    const int lane = threadIdx.x & 63;
    const int wid  = threadIdx.x >> 6;
    const int c = lane;
    const int pi = lane & 31;
    const bool hiHalf = lane >= 32;

    // W is (10,64) row-major. Fold cluster/center: W2 = W[k] + W[4+k] + W[7+k].
    float w2[4], wcl[3], wce[3];
    w2[3] = W[3 * OC + c];
    #pragma unroll
    for (int k = 0; k < 3; ++k) {
        wcl[k] = W[(4 + k) * OC + c];
        wce[k] = W[(7 + k) * OC + c];
        w2[k]  = W[k * OC + c] + wcl[k] + wce[k];
    }
    const float sgn = (gamma[c] >= 0.0f) ? 1.0f : -1.0f;
    #pragma unroll
    for (int k = 0; k < 3; ++k) { wcl[k] *= sgn; wce[k] *= sgn; w2[k] *= sgn; }
    w2[3] *= sgn;

    // Loop-invariant B fragments (w2', bf16). B[k][n]: col=lane&31, lanes<32
    // hold k0..7 (k0-3 = data), lanes>=32 hold k8..15 = zero.
    const uint32_t bw0 = pkbf16(w2[0], w2[1]);
    const uint32_t bw1 = pkbf16(w2[2], w2[3]);
    const uint32_t ob0 = (uint32_t)__shfl_xor((int)bw0, 32, 64);
    const uint32_t ob1 = (uint32_t)__shfl_xor((int)bw1, 32, 64);
    FRAG B0, B1;                                   // channels 0-31 / 32-63
    B0.u[0] = hiHalf ? 0u : bw0; B0.u[1] = hiHalf ? 0u : bw1; B0.u[2] = 0u; B0.u[3] = 0u;
    B1.u[0] = hiHalf ? 0u : ob0; B1.u[1] = hiHalf ? 0u : ob1; B1.u[2] = 0u; B1.u[3] = 0u;

    const float4* __restrict__ feat4 = reinterpret_cast<const float4*>(feat);

    float accS = 0.0f, accQ = 0.0f;
    float g0=0.f,g1=0.f,g2=0.f,g3=0.f,g4=0.f,g5=0.f,g6=0.f,g7=0.f,g8=0.f,g9=0.f;

    int t = blockIdx.x * 4 + wid;                  // always < NTASK at start
    float4 curv = feat4[(size_t)t * 64 + lane];

    for (; t < NTASK; t += NWAVES) {
        const int tu = __builtin_amdgcn_readfirstlane(t);
        const int tn = t + NWAVES;
        float4 nxtv = curv;
        if (tn < NTASK) nxtv = feat4[(size_t)tn * 64 + lane];   // prefetch

        const int nA = 2 * tu, nB = nA + 1;
        const int cntA = nump[nA], cntB = nump[nB];             // uniform s_load
        const int izA = coors[4*nA+1], iyA = coors[4*nA+2], ixA = coors[4*nA+3];
        const int izB = coors[4*nB+1], iyB = coors[4*nB+2], ixB = coors[4*nB+3];

        // mask this lane's point
        const int  myCnt = hiHalf ? cntB : cntA;
        const bool act = pi < myCnt;
        const float mx = act ? curv.x : 0.0f, my = act ? curv.y : 0.0f;
        const float mz = act ? curv.z : 0.0f, mw = act ? curv.w : 0.0f;

        // global Gram accumulation (per-lane, reduced once at kernel end)
        g0 = fmaf(mx, mx, g0); g1 = fmaf(my, my, g1); g2 = fmaf(mz, mz, g2);
        g3 = fmaf(mw, mw, g3); g4 = fmaf(mx, my, g4); g5 = fmaf(mx, mz, g5);
        g6 = fmaf(mx, mw, g6); g7 = fmaf(my, mz, g7); g8 = fmaf(my, mw, g8);
        g9 = fmaf(mz, mw, g9);

        // per-pillar feature sums (DPP butterfly within halves, then exchange)
        float s0 = red32(mx), s1 = red32(my), s2 = red32(mz), s3 = red32(mw);
        const float o0 = __shfl_xor(s0, 32, 64), o1 = __shfl_xor(s1, 32, 64);
        const float o2 = __shfl_xor(s2, 32, 64), o3 = __shfl_xor(s3, 32, 64);
        const float SA0 = hiHalf ? o0 : s0, SA1 = hiHalf ? o1 : s1;
        const float SA2 = hiHalf ? o2 : s2, SA3 = hiHalf ? o3 : s3;
        const float SB0 = hiHalf ? s0 : o0, SB1 = hiHalf ? s1 : o1;
        const float SB2 = hiHalf ? s2 : o2, SB3 = hiHalf ? s3 : o3;

        // A fragments: A[p][k], row=lane&31 (=point), lanes<32 k0..7, hi k8..15=0
        const uint32_t pk0 = pkbf16(mx, my), pk1 = pkbf16(mz, mw);
        const uint32_t qk0 = (uint32_t)__shfl_xor((int)pk0, 32, 64);
        const uint32_t qk1 = (uint32_t)__shfl_xor((int)pk1, 32, 64);
        FRAG AA, AB;
        AA.u[0] = hiHalf ? 0u : pk0; AA.u[1] = hiHalf ? 0u : pk1; AA.u[2] = 0u; AA.u[3] = 0u;
        AB.u[0] = hiHalf ? 0u : qk0; AB.u[1] = hiHalf ? 0u : qk1; AB.u[2] = 0u; AB.u[3] = 0u;

        // C masks: row = (reg&3) + 8*(reg>>2) + 4*(lane>>5); masked rows -> -3e38
        f32x16 CA, CB;
        #pragma unroll
        for (int r = 0; r < 16; ++r) {
            const int row = (r & 3) + 8 * (r >> 2) + (hiHalf ? 4 : 0);
            CA[r] = (row < cntA) ? 0.0f : -3.0e38f;
            CB[r] = (row < cntB) ? 0.0f : -3.0e38f;
        }

        f32x16 D;
        D = __builtin_amdgcn_mfma_f32_32x32x16_bf16(AA.v, B0.v, CA, 0, 0, 0);
        float mA0 = max16(D);
        D = __builtin_amdgcn_mfma_f32_32x32x16_bf16(AA.v, B1.v, CA, 0, 0, 0);
        float mA1 = max16(D);
        D = __builtin_amdgcn_mfma_f32_32x32x16_bf16(AB.v, B0.v, CB, 0, 0, 0);
        float mB0 = max16(D);
        D = __builtin_amdgcn_mfma_f32_32x32x16_bf16(AB.v, B1.v, CB, 0, 0, 0);
        float mB1 = max16(D);

        // combine point-halves; select channel tile (D col = lane&31)
        mA0 = fmaxf(mA0, __shfl_xor(mA0, 32, 64));
        mA1 = fmaxf(mA1, __shfl_xor(mA1, 32, 64));
        mB0 = fmaxf(mB0, __shfl_xor(mB0, 32, 64));
        mB1 = fmaxf(mB1, __shfl_xor(mB1, 32, 64));
        const float mA = hiHalf ? mA1 : mA0;   // max d' for channel=lane, pillar A
        const float mB = hiHalf ? mB1 : mB0;

        // epilogue pillar A
        {
            const float fcnt = (float)cntA, rc = __builtin_amdgcn_rcpf(fcnt);
            const float cz = ((float)izA + 0.5f) * 0.2f;
            const float cy = ((float)iyA + 0.5f) * 0.2f;
            const float cx = ((float)ixA + 0.5f) * 4.0f;
            const float mt   = fmaf(SA2, wcl[2], fmaf(SA1, wcl[1], SA0 * wcl[0]));
            const float bias = -fmaf(mt, rc, fmaf(cz, wce[0], fmaf(cy, wce[1], cx * wce[2])));
            const float ssum = fmaf(SA3, w2[3], fmaf(SA2, w2[2], fmaf(SA1, w2[1], SA0 * w2[0])));
            float hm = mA + bias;
            if (cntA < MP) hm = fmaxf(hm, 0.0f);
            hsel[(size_t)nA * OC + c] = sgn * hm;
            const float fb = fcnt * bias;
            accS = fmaf(sgn, ssum + fb, accS);
            accQ += fmaf(fb, bias, (bias + bias) * ssum);
        }
        // epilogue pillar B
        {
            const float fcnt = (float)cntB, rc = __builtin_amdgcn_rcpf(fcnt);
            const float cz = ((float)izB + 0.5f) * 0.2f;
            const float cy = ((float)iyB + 0.5f) * 0.2f;
            const float cx = ((float)ixB + 0.5f) * 4.0f;
            const float mt   = fmaf(SB2, wcl[2], fmaf(SB1, wcl[1], SB0 * wcl[0]));
            const float bias = -fmaf(mt, rc, fmaf(cz, wce[0], fmaf(cy, wce[1], cx * wce[2])));
            const float ssum = fmaf(SB3, w2[3], fmaf(SB2, w2[2], fmaf(SB1, w2[1], SB0 * w2[0])));
            float hm = mB + bias;
            if (cntB < MP) hm = fmaxf(hm, 0.0f);
            hsel[(size_t)nB * OC + c] = sgn * hm;
            const float fb = fcnt * bias;
            accS = fmaf(sgn, ssum + fb, accS);
            accQ += fmaf(fb, bias, (bias + bias) * ssum);
        }
        curv = nxtv;
    }

    // ---- final reductions
    sred[wid][c]      = accS;
    sred[wid][64 + c] = accQ;
    // Gram: full-wave reduce, lane0 stashes per-wave totals
    g0 = red32(g0); g0 += __shfl_xor(g0, 32, 64);
    g1 = red32(g1); g1 += __shfl_xor(g1, 32, 64);
    g2 = red32(g2); g2 += __shfl_xor(g2, 32, 64);
    g3 = red32(g3); g3 += __shfl_xor(g3, 32, 64);
    g4 = red32(g4); g4 += __shfl_xor(g4, 32, 64);
    g5 = red32(g5); g5 += __shfl_xor(g5, 32, 64);
    g6 = red32(g6); g6 += __shfl_xor(g6, 32, 64);
    g7 = red32(g7); g7 += __shfl_xor(g7, 32, 64);
    g8 = red32(g8); g8 += __shfl_xor(g8, 32, 64);
    g9 = red32(g9); g9 += __shfl_xor(g9, 32, 64);
    if (lane == 0) {
        sredG[wid][0] = g0; sredG[wid][1] = g1; sredG[wid][2] = g2;
        sredG[wid][3] = g3; sredG[wid][4] = g4; sredG[wid][5] = g5;
        sredG[wid][6] = g6; sredG[wid][7] = g7; sredG[wid][8] = g8;
        sredG[wid][9] = g9;
    }
    __syncthreads();
    if (wid == 0) {
        const float s  = sred[0][lane] + sred[1][lane] + sred[2][lane] + sred[3][lane];
        const float sq = sred[0][64+lane] + sred[1][64+lane] + sred[2][64+lane] + sred[3][64+lane];
        atomicAdd(&accum[lane],      (unsigned long long)(long long)llrintf(s  * FIXS_S));
        atomicAdd(&accum[64 + lane], (unsigned long long)(long long)llrintf(sq * FIXS_Q));
        if (lane < 10) {
            const float g = sredG[0][lane] + sredG[1][lane] + sredG[2][lane] + sredG[3][lane];
            atomicAdd(&accum[128 + lane], (unsigned long long)(long long)llrintf(g * FIXS_G));
        }
    }
}

// ---------------------------------------------------------------------------
// Finalize BN stats -> per-channel scale/shift. Sigma h^2 = w2^T G w2 + biaspart.
// ---------------------------------------------------------------------------
__global__ void sap_finalize(const unsigned long long* __restrict__ accum,
                             const float* __restrict__ W,
                             const float* __restrict__ gamma,
                             const float* __restrict__ beta,
                             float* __restrict__ scsh)
{
    const int c = threadIdx.x;
    double G[10];
    #pragma unroll
    for (int k = 0; k < 10; ++k)
        G[k] = (double)(long long)accum[128 + k] * (1.0 / 1048576.0);
    double w[4];
    w[3] = (double)W[3 * OC + c];
    #pragma unroll
    for (int k = 0; k < 3; ++k)
        w[k] = (double)W[k * OC + c] + (double)W[(4 + k) * OC + c] + (double)W[(7 + k) * OC + c];
    const double q = w[0]*w[0]*G[0] + w[1]*w[1]*G[1] + w[2]*w[2]*G[2] + w[3]*w[3]*G[3]
        + 2.0 * (w[0]*w[1]*G[4] + w[0]*w[2]*G[5] + w[0]*w[3]*G[6]
               + w[1]*w[2]*G[7] + w[1]*w[3]*G[8] + w[2]*w[3]*G[9]);
    const double S  = (double)(long long)accum[c]      * (1.0 / 65536.0);
    const double Qb = (double)(long long)accum[64 + c] * (1.0 / 256.0);
    const double mu_d  = S / MTOT;
    const double var_d = (q + Qb) / MTOT - mu_d * mu_d;
    const float mu = (float)mu_d;
    const float sc = gamma[c] * rsqrtf((float)var_d + BNEPS);
    const float sh = beta[c] - mu * sc;
    scsh[c]      = sc;
    scsh[64 + c] = sh;
}

// ---------------------------------------------------------------------------
// Pass 2: in-place over d_out: out = relu(scale * hsel + shift).
// ---------------------------------------------------------------------------
__global__ __launch_bounds__(256) void sap_pass2(const float* __restrict__ scsh,
                                                 float* __restrict__ out)
{
    const int idx = blockIdx.x * 256 + threadIdx.x;
    if (idx >= (NP * OC) / 4) return;
    float4 h = reinterpret_cast<float4*>(out)[idx];
    const int ci = idx & 15;                               // channel quad (64ch/4)
    const float4 sc = reinterpret_cast<const float4*>(scsh)[ci];
    const float4 sh = reinterpret_cast<const float4*>(scsh + 64)[ci];
    float4 o;
    o.x = fmaxf(fmaf(h.x, sc.x, sh.x), 0.0f);
    o.y = fmaxf(fmaf(h.y, sc.y, sh.y), 0.0f);
    o.z = fmaxf(fmaf(h.z, sc.z, sh.z), 0.0f);
    o.w = fmaxf(fmaf(h.w, sc.w, sh.w), 0.0f);
    reinterpret_cast<float4*>(out)[idx] = o;
}

extern "C" void kernel_launch(void* const* d_in, const int* in_sizes, int n_in,
                              void* d_out, int out_size, void* d_ws, size_t ws_size,
                              hipStream_t stream) {
    const float* feat  = (const float*)d_in[0];
    const float* W     = (const float*)d_in[1];
    const float* gamma = (const float*)d_in[2];
    const float* beta  = (const float*)d_in[3];
    const int*   nump  = (const int*)d_in[4];
    const int*   coors = (const int*)d_in[5];
    float* out = (float*)d_out;

    unsigned long long* accum = (unsigned long long*)d_ws;   // 138 * 8B
    float* scsh = (float*)((char*)d_ws + 2048);              // 128 * 4B

    hipMemsetAsync(d_ws, 0, 2048, stream);
    // Pass 1 writes its per-pillar max/min selection straight into d_out.
    sap_pass1<<<GRID1, 256, 0, stream>>>(feat, W, gamma, nump, coors, out, accum);
    sap_finalize<<<1, 64, 0, stream>>>(accum, W, gamma, beta, scsh);
    sap_pass2<<<(NP * OC / 4 + 255) / 256, 256, 0, stream>>>(scsh, out);
}

// Round 9
// 77.866 us; speedup vs baseline: 1.5011x; 1.0470x over previous
//
#include <hip/hip_runtime.h>
#include <stdint.h>

#define NP 100000
#define MP 32
#define OC 64
#define NGROUP 1563               // ceil(NP/64) pillar-groups, one per wave
#define NBLK 391                  // ceil(NGROUP/4), 4 waves per block
#define BNEPS 0.001f
#define MTOT 3200000.0
// upper-triangular index into the 10x10 Gram (i<=j), 55 entries
#define GIDX(i,j) ((i)*10 - (i)*((i)-1)/2 + ((j)-(i)))

// ---- cross-lane helpers (VALU DPP + 1 swizzle + 1 bpermute), from r8 ----
__device__ __forceinline__ float red32(float v) {
    v += __int_as_float(__builtin_amdgcn_update_dpp(0, __float_as_int(v), 0xB1,  0xF, 0xF, true)); // xor1
    v += __int_as_float(__builtin_amdgcn_update_dpp(0, __float_as_int(v), 0x4E,  0xF, 0xF, true)); // xor2
    v += __int_as_float(__builtin_amdgcn_update_dpp(0, __float_as_int(v), 0x141, 0xF, 0xF, true)); // xor4
    v += __int_as_float(__builtin_amdgcn_update_dpp(0, __float_as_int(v), 0x140, 0xF, 0xF, true)); // xor8
    v += __int_as_float(__builtin_amdgcn_ds_swizzle(__float_as_int(v), 0x401F));                   // xor16
    return v;
}
__device__ __forceinline__ float redall(float v) {   // full 64-lane sum
    v = red32(v);
    v += __shfl_xor(v, 32, 64);
    return v;
}

// ---------------------------------------------------------------------------
// Prep: fold weights per channel into wtab[c] = {sgn*w2[4], sgn*wcl[3],
// sgn*wce[3], sgn, pad} (16 floats, 64B) and zero the stat accumulators.
// ---------------------------------------------------------------------------
__global__ void sap_prep(const float* __restrict__ W, const float* __restrict__ gamma,
                         float* __restrict__ wtab, unsigned long long* __restrict__ accum)
{
    const int c = threadIdx.x;   // 64 threads
    float w2[4], wcl[3], wce[3];
    w2[3] = W[3 * OC + c];
    #pragma unroll
    for (int k = 0; k < 3; ++k) {
        wcl[k] = W[(4 + k) * OC + c];
        wce[k] = W[(7 + k) * OC + c];
        w2[k]  = W[k * OC + c] + wcl[k] + wce[k];
    }
    const float sgn = (gamma[c] >= 0.0f) ? 1.0f : -1.0f;
    float* o = wtab + c * 16;
    #pragma unroll
    for (int k = 0; k < 4; ++k) o[k] = w2[k] * sgn;
    #pragma unroll
    for (int k = 0; k < 3; ++k) { o[4 + k] = wcl[k] * sgn; o[7 + k] = wce[k] * sgn; }
    o[10] = sgn; o[11] = 0.f; o[12] = 0.f; o[13] = 0.f; o[14] = 0.f; o[15] = 0.f;
    if (c < 62) accum[c] = 0ull;
}

// ---------------------------------------------------------------------------
// Pass 1: LANE = PILLAR. Zero broadcasts, zero scalar per-pillar loads.
// Per wave: 64 pillars fully register-resident (32 x float4 per lane).
//  A) mask + per-pillar sums;  C) 64-channel max loop (4 FMA + 1 max per
//  point, SGPR weights, NEG seed excludes masked);  B) 10-dim masked-feature
//  Gram (global BN stats via quadratic form);  end: wave+block reduce -> 62
//  fixed-point atomics.
// ---------------------------------------------------------------------------
__global__ __launch_bounds__(256, 2) void sap_pass1(
    const float4* __restrict__ feat4, const int* __restrict__ nump,
    const int4* __restrict__ coors4, const float* __restrict__ wtab,
    float* __restrict__ hsel, unsigned long long* __restrict__ accum)
{
    __shared__ float red[4][64];
    const int lane = threadIdx.x & 63;
    const int wid  = threadIdx.x >> 6;
    const int grp  = blockIdx.x * 4 + wid;

    float G[55];
    #pragma unroll
    for (int k = 0; k < 55; ++k) G[k] = 0.0f;
    float S0 = 0.f, S1 = 0.f, S2 = 0.f, S3 = 0.f;
    float E0 = 0.f, E1 = 0.f, E2 = 0.f;

    if (grp < NGROUP) {
        const int n = grp * 64 + lane;
        const bool valid = n < NP;
        const int nn = valid ? n : NP - 1;
        const int cnt = valid ? nump[nn] : 0;          // coalesced vector load
        const int4 cr = coors4[nn];                    // coalesced 16B/lane
        const float cenz = ((float)cr.y + 0.5f) * 0.2f;   // coors[1] * vs0
        const float ceny = ((float)cr.z + 0.5f) * 0.2f;   // coors[2] * vs1
        const float cenx = ((float)cr.w + 0.5f) * 4.0f;   // coors[3] * vs2

        // ---- load this lane's pillar (512B; 64B-line reuse across p%4)
        float4 F[32];
        const float4* __restrict__ fp = feat4 + (size_t)nn * MP;
        #pragma unroll
        for (int p = 0; p < MP; ++p) F[p] = fp[p];

        // ---- A: mask, sums, NEG seeds
        float NEG[32];
        #pragma unroll
        for (int p = 0; p < MP; ++p) {
            const bool act = p < cnt;
            float4 f = F[p];
            f.x = act ? f.x : 0.0f; f.y = act ? f.y : 0.0f;
            f.z = act ? f.z : 0.0f; f.w = act ? f.w : 0.0f;
            F[p] = f;
            NEG[p] = act ? 0.0f : -3.0e38f;
            S0 += f.x; S1 += f.y; S2 += f.z; S3 += f.w;
        }
        const float fcnt = (float)cnt;
        const float rc = __builtin_amdgcn_rcpf(fmaxf(fcnt, 1.0f));
        const float mx = S0 * rc, my = S1 * rc, mz = S2 * rc;
        const float fl = (cnt < MP) ? 0.0f : -3.0e38f;   // masked-h'=0 floor

        // ---- C: channel loop; weights via uniform (SGPR) loads from wtab
        const float4* __restrict__ wt4 = reinterpret_cast<const float4*>(wtab);
        #pragma unroll 1
        for (int ch = 0; ch < 4; ++ch) {
            #pragma unroll 1
            for (int c4 = 0; c4 < 4; ++c4) {
                float o[4];
                #pragma unroll
                for (int cc = 0; cc < 4; ++cc) {
                    const int c = ch * 16 + c4 * 4 + cc;
                    const float4 wa = wt4[c * 4];       // w2'[0..3]
                    const float4 wb = wt4[c * 4 + 1];   // wcl'[0..2], wce'[0]
                    const float4 wc = wt4[c * 4 + 2];   // wce'[1..2], sgn, 0
                    float m0 = -3.0e38f, m1 = -3.0e38f;
                    #pragma unroll
                    for (int p = 0; p < MP; p += 2) {
                        const float d0 = fmaf(F[p].x, wa.x, fmaf(F[p].y, wa.y,
                                         fmaf(F[p].z, wa.z, fmaf(F[p].w, wa.w, NEG[p]))));
                        const float d1 = fmaf(F[p+1].x, wa.x, fmaf(F[p+1].y, wa.y,
                                         fmaf(F[p+1].z, wa.z, fmaf(F[p+1].w, wa.w, NEG[p+1]))));
                        m0 = fmaxf(m0, d0); m1 = fmaxf(m1, d1);
                    }
                    const float m = fmaxf(m0, m1);
                    const float bias = -(mx * wb.x + my * wb.y + mz * wb.z
                                       + cenz * wb.w + ceny * wc.x + cenx * wc.y);
                    o[cc] = wc.z * fmaxf(m + bias, fl);
                }
                if (valid) {
                    float4 st = make_float4(o[0], o[1], o[2], o[3]);
                    *reinterpret_cast<float4*>(hsel + (size_t)n * OC + ch * 16 + c4 * 4) = st;
                }
            }
        }

        // ---- B: 10-dim masked-g Gram (global BN stats)
        #pragma unroll
        for (int p = 0; p < MP; ++p) {
            const float actf = (p < cnt) ? 1.0f : 0.0f;
            const float4 f = F[p];                     // already masked
            float g[10];
            g[0] = f.x; g[1] = f.y; g[2] = f.z; g[3] = f.w;
            g[4] = fmaf(-mx,   actf, f.x);             // f_cluster (0 when masked)
            g[5] = fmaf(-my,   actf, f.y);
            g[6] = fmaf(-mz,   actf, f.z);
            g[7] = fmaf(-cenz, actf, f.x);             // f_center (0 when masked)
            g[8] = fmaf(-ceny, actf, f.y);
            g[9] = fmaf(-cenx, actf, f.z);
            #pragma unroll
            for (int i = 0; i < 10; ++i)
                #pragma unroll
                for (int j = i; j < 10; ++j)
                    G[GIDX(i, j)] = fmaf(g[i], g[j], G[GIDX(i, j)]);
        }
        // linear g-sums: Sg[0..3]=S, Sg[4..6]=0 exactly, Sg[7..9] analytic
        E0 = fmaf(-fcnt, cenz, S0);
        E1 = fmaf(-fcnt, ceny, S1);
        E2 = fmaf(-fcnt, cenx, S2);
    }

    // ---- reduce 62 stats across the wave, then the block, then atomics
    #pragma unroll
    for (int k = 0; k < 55; ++k) G[k] = redall(G[k]);
    S0 = redall(S0); S1 = redall(S1); S2 = redall(S2); S3 = redall(S3);
    E0 = redall(E0); E1 = redall(E1); E2 = redall(E2);
    if (lane == 0) {
        #pragma unroll
        for (int k = 0; k < 55; ++k) red[wid][k] = G[k];
        red[wid][55] = S0; red[wid][56] = S1; red[wid][57] = S2; red[wid][58] = S3;
        red[wid][59] = E0; red[wid][60] = E1; red[wid][61] = E2;
    }
    __syncthreads();
    if (wid == 0 && lane < 62) {
        const float s = red[0][lane] + red[1][lane] + red[2][lane] + red[3][lane];
        atomicAdd(&accum[lane], (unsigned long long)(long long)llrintf(s * 256.0f));
    }
}

// ---------------------------------------------------------------------------
// Finalize: mu[c] = Sg.W[:,c]/MTOT, E[h^2][c] = W[:,c]^T G W[:,c]/MTOT (fp64).
// ---------------------------------------------------------------------------
__global__ void sap_finalize(const unsigned long long* __restrict__ accum,
                             const float* __restrict__ W,
                             const float* __restrict__ gamma,
                             const float* __restrict__ beta,
                             float* __restrict__ scsh)
{
    const int c = threadIdx.x;   // 64
    double G[55];
    for (int k = 0; k < 55; ++k) G[k] = (double)(long long)accum[k] * (1.0 / 256.0);
    double Sg[10];
    Sg[0] = (double)(long long)accum[55] * (1.0 / 256.0);
    Sg[1] = (double)(long long)accum[56] * (1.0 / 256.0);
    Sg[2] = (double)(long long)accum[57] * (1.0 / 256.0);
    Sg[3] = (double)(long long)accum[58] * (1.0 / 256.0);
    Sg[4] = 0.0; Sg[5] = 0.0; Sg[6] = 0.0;
    Sg[7] = (double)(long long)accum[59] * (1.0 / 256.0);
    Sg[8] = (double)(long long)accum[60] * (1.0 / 256.0);
    Sg[9] = (double)(long long)accum[61] * (1.0 / 256.0);
    double w[10];
    for (int k = 0; k < 10; ++k) w[k] = (double)W[k * OC + c];
    double sh = 0.0, q = 0.0;
    for (int k = 0; k < 10; ++k) sh += Sg[k] * w[k];
    for (int i = 0; i < 10; ++i)
        for (int j = i; j < 10; ++j) {
            const double t = w[i] * w[j] * G[GIDX(i, j)];
            q += (i == j) ? t : 2.0 * t;
        }
    const double mu_d = sh / MTOT;
    const double var_d = q / MTOT - mu_d * mu_d;
    const float sc = gamma[c] * rsqrtf((float)var_d + BNEPS);
    scsh[c]      = sc;
    scsh[64 + c] = beta[c] - (float)mu_d * sc;
}

// ---------------------------------------------------------------------------
// Pass 2: in-place over d_out: out = relu(scale * hsel + shift).
// ---------------------------------------------------------------------------
__global__ __launch_bounds__(256) void sap_pass2(const float* __restrict__ scsh,
                                                 float* __restrict__ out)
{
    const int idx = blockIdx.x * 256 + threadIdx.x;
    if (idx >= (NP * OC) / 4) return;
    float4 h = reinterpret_cast<float4*>(out)[idx];
    const int ci = idx & 15;
    const float4 sc = reinterpret_cast<const float4*>(scsh)[ci];
    const float4 sh = reinterpret_cast<const float4*>(scsh + 64)[ci];
    float4 o;
    o.x = fmaxf(fmaf(h.x, sc.x, sh.x), 0.0f);
    o.y = fmaxf(fmaf(h.y, sc.y, sh.y), 0.0f);
    o.z = fmaxf(fmaf(h.z, sc.z, sh.z), 0.0f);
    o.w = fmaxf(fmaf(h.w, sc.w, sh.w), 0.0f);
    reinterpret_cast<float4*>(out)[idx] = o;
}

extern "C" void kernel_launch(void* const* d_in, const int* in_sizes, int n_in,
                              void* d_out, int out_size, void* d_ws, size_t ws_size,
                              hipStream_t stream) {
    const float* feat  = (const float*)d_in[0];
    const float* W     = (const float*)d_in[1];
    const float* gamma = (const float*)d_in[2];
    const float* beta  = (const float*)d_in[3];
    const int*   nump  = (const int*)d_in[4];
    const int*   coors = (const int*)d_in[5];
    float* out = (float*)d_out;

    float* wtab = (float*)d_ws;                                       // 4 KB
    unsigned long long* accum = (unsigned long long*)((char*)d_ws + 4096); // 62*8B
    float* scsh = (float*)((char*)d_ws + 8192);                       // 512 B

    sap_prep<<<1, 64, 0, stream>>>(W, gamma, wtab, accum);
    sap_pass1<<<NBLK, 256, 0, stream>>>(
        (const float4*)feat, nump, (const int4*)coors, wtab, out, accum);
    sap_finalize<<<1, 64, 0, stream>>>(accum, W, gamma, beta, scsh);
    sap_pass2<<<(NP * OC / 4 + 255) / 256, 256, 0, stream>>>(scsh, out);
}

// Round 10
// 77.364 us; speedup vs baseline: 1.5109x; 1.0065x over previous
//
#include <hip/hip_runtime.h>
#include <stdint.h>

#define NP 100000
#define MP 32
#define OC 64
#define NBLK 1563                 // ceil(NP/64): one 64-pillar group per block
#define BNEPS 0.001f
#define MTOT 3200000.0
#define GIDX(i,j) ((i)*10 - (i)*((i)-1)/2 + ((j)-(i)))   // 10x10 upper-tri, 55
#define BG(a,b) B[((a)<=(b)) ? ((a)*(7-(a))/2+(b)) : ((b)*(7-(b))/2+(a))]  // 4x4 upper-tri, 10

// ---- 64-lane sum (DPP butterfly + swizzle + half exchange) ----
__device__ __forceinline__ float redall(float v) {
    v += __int_as_float(__builtin_amdgcn_update_dpp(0, __float_as_int(v), 0xB1,  0xF, 0xF, true));
    v += __int_as_float(__builtin_amdgcn_update_dpp(0, __float_as_int(v), 0x4E,  0xF, 0xF, true));
    v += __int_as_float(__builtin_amdgcn_update_dpp(0, __float_as_int(v), 0x141, 0xF, 0xF, true));
    v += __int_as_float(__builtin_amdgcn_update_dpp(0, __float_as_int(v), 0x140, 0xF, 0xF, true));
    v += __int_as_float(__builtin_amdgcn_ds_swizzle(__float_as_int(v), 0x401F));
    v += __shfl_xor(v, 32, 64);
    return v;
}

// ---------------------------------------------------------------------------
// Prep: per-channel folded weights. w2tab[c] = sgn*{w2[0..3]};
// btab[2c]={sgn*wcl[0..2], sgn*wce[0]}, btab[2c+1]={sgn*wce[1..2], sgn, 0}.
// ---------------------------------------------------------------------------
__global__ void sap_prep(const float* __restrict__ W, const float* __restrict__ gamma,
                         float4* __restrict__ w2tab, float4* __restrict__ btab,
                         unsigned long long* __restrict__ accum)
{
    const int c = threadIdx.x;   // 64
    float w2[4], wcl[3], wce[3];
    w2[3] = W[3 * OC + c];
    #pragma unroll
    for (int k = 0; k < 3; ++k) {
        wcl[k] = W[(4 + k) * OC + c];
        wce[k] = W[(7 + k) * OC + c];
        w2[k]  = W[k * OC + c] + wcl[k] + wce[k];
    }
    const float sgn = (gamma[c] >= 0.0f) ? 1.0f : -1.0f;
    w2tab[c] = make_float4(w2[0]*sgn, w2[1]*sgn, w2[2]*sgn, w2[3]*sgn);
    btab[2*c]   = make_float4(wcl[0]*sgn, wcl[1]*sgn, wcl[2]*sgn, wce[0]*sgn);
    btab[2*c+1] = make_float4(wce[1]*sgn, wce[2]*sgn, sgn, 0.0f);
    if (c < 62) accum[c] = 0ull;
}

// ---------------------------------------------------------------------------
// Pass 1: LANE = PILLAR (streamed). Block = 64 pillars; wave wid owns channels
// [wid*16, wid*16+16) with weights in SGPRs (readfirstlane-forced). Per point:
// 1 load + 16x(4 FMA + max); masked points excluded by -3e38 FMA seed.
// Wave 0 additionally accumulates the raw 4x4 moment B and converts it to the
// 10x10 masked-feature Gram via closed-form per-pillar corrections.
// ---------------------------------------------------------------------------
__global__ __launch_bounds__(256, 4) void sap_pass1(
    const float4* __restrict__ feat4, const int* __restrict__ nump,
    const int4* __restrict__ coors4, const float4* __restrict__ w2tab,
    const float4* __restrict__ btab, float* __restrict__ hsel,
    unsigned long long* __restrict__ accum)
{
    const int lane = threadIdx.x & 63;
    const int swid = __builtin_amdgcn_readfirstlane(threadIdx.x >> 6);  // scalar
    const int n = blockIdx.x * 64 + lane;
    const bool valid = n < NP;
    const int nn = valid ? n : NP - 1;
    const int cnt = valid ? nump[nn] : 0;          // coalesced
    const int4 cr = coors4[nn];                    // coalesced 16B
    const float cenz = ((float)cr.y + 0.5f) * 0.2f;
    const float ceny = ((float)cr.z + 0.5f) * 0.2f;
    const float cenx = ((float)cr.w + 0.5f) * 4.0f;
    const float4* __restrict__ fp = feat4 + (size_t)nn * MP;

    // wave's 16 channels -> SGPRs (uniform swid-based index => s_load)
    float4 wv[16];
    #pragma unroll
    for (int cc = 0; cc < 16; ++cc) wv[cc] = w2tab[swid * 16 + cc];

    float mac[16];
    #pragma unroll
    for (int cc = 0; cc < 16; ++cc) mac[cc] = -3.0e38f;
    float S0 = 0.f, S1 = 0.f, S2 = 0.f, S3 = 0.f;
    float B[10];
    #pragma unroll
    for (int k = 0; k < 10; ++k) B[k] = 0.f;

#define POINT(FF, P, DOB) {                                                     \
    const bool act = (P) < cnt;                                                 \
    const float neg = act ? 0.0f : -3.0e38f;                                    \
    const float ax = act ? (FF).x : 0.0f, ay = act ? (FF).y : 0.0f;             \
    const float az = act ? (FF).z : 0.0f;                                       \
    S0 += ax; S1 += ay; S2 += az;                                               \
    if (DOB) {                                                                  \
        const float aw = act ? (FF).w : 0.0f;                                   \
        S3 += aw;                                                               \
        B[0]=fmaf(ax,ax,B[0]); B[1]=fmaf(ax,ay,B[1]); B[2]=fmaf(ax,az,B[2]);    \
        B[3]=fmaf(ax,aw,B[3]); B[4]=fmaf(ay,ay,B[4]); B[5]=fmaf(ay,az,B[5]);    \
        B[6]=fmaf(ay,aw,B[6]); B[7]=fmaf(az,az,B[7]); B[8]=fmaf(az,aw,B[8]);    \
        B[9]=fmaf(aw,aw,B[9]);                                                  \
    }                                                                           \
    _Pragma("unroll")                                                           \
    for (int cc = 0; cc < 16; ++cc) {                                           \
        const float d = fmaf((FF).x, wv[cc].x, fmaf((FF).y, wv[cc].y,           \
                        fmaf((FF).z, wv[cc].z, fmaf((FF).w, wv[cc].w, neg))));  \
        mac[cc] = fmaxf(mac[cc], d);                                            \
    } }

#define PQLOOP(DOB) {                                                           \
    float4 b0 = fp[0], b1 = fp[1], b2 = fp[2], b3 = fp[3];                      \
    _Pragma("unroll 1")                                                         \
    for (int pq = 0; pq < 8; ++pq) {                                            \
        const int pb = pq * 4;                                                  \
        float4 n0 = b0, n1 = b1, n2 = b2, n3 = b3;                              \
        if (pq < 7) { n0 = fp[pb+4]; n1 = fp[pb+5]; n2 = fp[pb+6]; n3 = fp[pb+7]; } \
        POINT(b0, pb + 0, DOB) POINT(b1, pb + 1, DOB)                           \
        POINT(b2, pb + 2, DOB) POINT(b3, pb + 3, DOB)                           \
        b0 = n0; b1 = n1; b2 = n2; b3 = n3;                                     \
    } }

    if (swid == 0) PQLOOP(true) else PQLOOP(false)
#undef PQLOOP
#undef POINT

    // ---- epilogue: bias + floor + store (16 channels, 4x float4)
    const float fcnt = (float)cnt;
    const float rc = __builtin_amdgcn_rcpf(fmaxf(fcnt, 1.0f));
    const float mx = S0 * rc, my = S1 * rc, mz = S2 * rc;
    const float fl = (cnt < MP) ? 0.0f : -3.0e38f;
    #pragma unroll
    for (int q = 0; q < 4; ++q) {
        float o[4];
        #pragma unroll
        for (int k = 0; k < 4; ++k) {
            const int c = swid * 16 + q * 4 + k;
            const float4 bA = btab[2 * c];       // wcl0..2, wce0  (sgn-folded)
            const float4 bB = btab[2 * c + 1];   // wce1..2, sgn, 0
            const float bias = -(mx * bA.x + my * bA.y + mz * bA.z
                               + cenz * bA.w + ceny * bB.x + cenx * bB.y);
            o[k] = bB.z * fmaxf(mac[q * 4 + k] + bias, fl);
        }
        if (valid)
            *reinterpret_cast<float4*>(hsel + (size_t)n * OC + swid * 16 + q * 4)
                = make_float4(o[0], o[1], o[2], o[3]);
    }

    // ---- wave 0: per-pillar Gram corrections -> 62 global stats
    if (swid == 0) {
        float vals[62];
        const float Sf[4] = {S0, S1, S2, S3};
        const float mu[3] = {S0 * rc, S1 * rc, S2 * rc};
        const float ce[3] = {cenz, ceny, cenx};
        #pragma unroll
        for (int i = 0; i < 4; ++i)
            #pragma unroll
            for (int j = i; j < 4; ++j)
                vals[GIDX(i, j)] = BG(i, j);
        #pragma unroll
        for (int i = 0; i < 4; ++i)
            #pragma unroll
            for (int t = 0; t < 3; ++t)
                vals[GIDX(i, 4 + t)] = BG(i, t) - mu[t] * Sf[i];
        #pragma unroll
        for (int s = 0; s < 3; ++s)
            #pragma unroll
            for (int t = s; t < 3; ++t)
                vals[GIDX(4 + s, 4 + t)] = BG(s, t) - mu[s] * Sf[t];
        #pragma unroll
        for (int i = 0; i < 4; ++i)
            #pragma unroll
            for (int t = 0; t < 3; ++t)
                vals[GIDX(i, 7 + t)] = BG(i, t) - ce[t] * Sf[i];
        #pragma unroll
        for (int s = 0; s < 3; ++s)
            #pragma unroll
            for (int t = 0; t < 3; ++t)
                vals[GIDX(4 + s, 7 + t)] = BG(s, t) - mu[s] * Sf[t];
        #pragma unroll
        for (int s = 0; s < 3; ++s)
            #pragma unroll
            for (int t = s; t < 3; ++t)
                vals[GIDX(7 + s, 7 + t)] =
                    fmaf(fcnt * ce[s], ce[t], BG(s, t) - ce[s] * Sf[t] - ce[t] * Sf[s]);
        vals[55] = S0; vals[56] = S1; vals[57] = S2; vals[58] = S3;
        vals[59] = fmaf(-fcnt, cenz, S0);
        vals[60] = fmaf(-fcnt, ceny, S1);
        vals[61] = fmaf(-fcnt, cenx, S2);

        #pragma unroll
        for (int k = 0; k < 62; ++k) vals[k] = redall(vals[k]);
        float mine = 0.0f;
        #pragma unroll
        for (int k = 0; k < 62; ++k) mine = (lane == k) ? vals[k] : mine;
        if (lane < 62)
            atomicAdd(&accum[lane],
                      (unsigned long long)(long long)llrintf(mine * 256.0f));
    }
}

// ---------------------------------------------------------------------------
// Finalize: mu[c] = Sg.W[:,c]/MTOT, E[h^2][c] = W[:,c]^T G W[:,c]/MTOT (fp64).
// ---------------------------------------------------------------------------
__global__ void sap_finalize(const unsigned long long* __restrict__ accum,
                             const float* __restrict__ W,
                             const float* __restrict__ gamma,
                             const float* __restrict__ beta,
                             float* __restrict__ scsh)
{
    const int c = threadIdx.x;   // 64
    double G[55];
    for (int k = 0; k < 55; ++k) G[k] = (double)(long long)accum[k] * (1.0 / 256.0);
    double Sg[10];
    Sg[0] = (double)(long long)accum[55] * (1.0 / 256.0);
    Sg[1] = (double)(long long)accum[56] * (1.0 / 256.0);
    Sg[2] = (double)(long long)accum[57] * (1.0 / 256.0);
    Sg[3] = (double)(long long)accum[58] * (1.0 / 256.0);
    Sg[4] = 0.0; Sg[5] = 0.0; Sg[6] = 0.0;
    Sg[7] = (double)(long long)accum[59] * (1.0 / 256.0);
    Sg[8] = (double)(long long)accum[60] * (1.0 / 256.0);
    Sg[9] = (double)(long long)accum[61] * (1.0 / 256.0);
    double w[10];
    for (int k = 0; k < 10; ++k) w[k] = (double)W[k * OC + c];
    double sh = 0.0, q = 0.0;
    for (int k = 0; k < 10; ++k) sh += Sg[k] * w[k];
    for (int i = 0; i < 10; ++i)
        for (int j = i; j < 10; ++j) {
            const double t = w[i] * w[j] * G[GIDX(i, j)];
            q += (i == j) ? t : 2.0 * t;
        }
    const double mu_d = sh / MTOT;
    const double var_d = q / MTOT - mu_d * mu_d;
    const float sc = gamma[c] * rsqrtf((float)var_d + BNEPS);
    scsh[c]      = sc;
    scsh[64 + c] = beta[c] - (float)mu_d * sc;
}

// ---------------------------------------------------------------------------
// Pass 2: in-place over d_out: out = relu(scale * hsel + shift).
// ---------------------------------------------------------------------------
__global__ __launch_bounds__(256) void sap_pass2(const float* __restrict__ scsh,
                                                 float* __restrict__ out)
{
    const int idx = blockIdx.x * 256 + threadIdx.x;
    if (idx >= (NP * OC) / 4) return;
    float4 h = reinterpret_cast<float4*>(out)[idx];
    const int ci = idx & 15;
    const float4 sc = reinterpret_cast<const float4*>(scsh)[ci];
    const float4 sh = reinterpret_cast<const float4*>(scsh + 64)[ci];
    float4 o;
    o.x = fmaxf(fmaf(h.x, sc.x, sh.x), 0.0f);
    o.y = fmaxf(fmaf(h.y, sc.y, sh.y), 0.0f);
    o.z = fmaxf(fmaf(h.z, sc.z, sh.z), 0.0f);
    o.w = fmaxf(fmaf(h.w, sc.w, sh.w), 0.0f);
    reinterpret_cast<float4*>(out)[idx] = o;
}

extern "C" void kernel_launch(void* const* d_in, const int* in_sizes, int n_in,
                              void* d_out, int out_size, void* d_ws, size_t ws_size,
                              hipStream_t stream) {
    const float* feat  = (const float*)d_in[0];
    const float* W     = (const float*)d_in[1];
    const float* gamma = (const float*)d_in[2];
    const float* beta  = (const float*)d_in[3];
    const int*   nump  = (const int*)d_in[4];
    const int*   coors = (const int*)d_in[5];
    float* out = (float*)d_out;

    float4* w2tab = (float4*)d_ws;                                      // 1 KB
    float4* btab  = (float4*)((char*)d_ws + 1024);                      // 2 KB
    unsigned long long* accum = (unsigned long long*)((char*)d_ws + 3072); // 496 B
    float* scsh = (float*)((char*)d_ws + 4096);                         // 512 B

    sap_prep<<<1, 64, 0, stream>>>(W, gamma, w2tab, btab, accum);
    sap_pass1<<<NBLK, 256, 0, stream>>>(
        (const float4*)feat, nump, (const int4*)coors, w2tab, btab, out, accum);
    sap_finalize<<<1, 64, 0, stream>>>(accum, W, gamma, beta, scsh);
    sap_pass2<<<(NP * OC / 4 + 255) / 256, 256, 0, stream>>>(scsh, out);
}